// Round 1
// baseline (11750.494 us; speedup 1.0000x reference)
//
#include <hip/hip_runtime.h>
#include <hip/hip_bf16.h>

#define BB 64
#define VV 2048
#define ENCD 128
#define TT 100
#define EMBD 256
#define DECD 512
#define ATTD 256
#define NVOCAB 29

typedef unsigned int u32;
typedef unsigned short u16;

__device__ __forceinline__ float sigf(float x) { return 1.0f / (1.0f + __expf(-x)); }

// ---------------- one-time init kernels ----------------

// Transpose W_dec [ATT][DEC] -> W_decT [DEC][ATT], W_beta [ENC][DEC] -> W_betaT [DEC][ENC]
__global__ __launch_bounds__(256) void k_transpose(const float* __restrict__ W_dec,
                                                   const float* __restrict__ W_beta,
                                                   float* __restrict__ W_decT,
                                                   float* __restrict__ W_betaT) {
    int i = blockIdx.x * 256 + threadIdx.x;
    if (i < DECD * ATTD) {
        int l = i / ATTD, a = i % ATTD;
        W_decT[i] = W_dec[a * DECD + l];
    }
    int j = i - DECD * ATTD;
    if (j >= 0 && j < DECD * ENCD) {
        int l = j / ENCD, e = j % ENCD;
        W_betaT[j] = W_beta[e * DECD + l];
    }
}

// enc_attT[b][a][v] = bf16( enc[b][v][:] . W_enc[a][:] + b_enc[a] )
__global__ __launch_bounds__(256) void k_enc_att(const float* __restrict__ enc,
                                                 const float* __restrict__ W_enc,
                                                 const float* __restrict__ b_enc,
                                                 u16* __restrict__ enc_attT) {
    __shared__ float tile[64][ENCD + 1];   // +1 pad: breaks 32-way bank aliasing on tile[vl][k]
    int b = blockIdx.y, v0 = blockIdx.x * 64;
    int t = threadIdx.x;
    const float* src = enc + ((size_t)b * VV + v0) * ENCD;
    for (int i = t; i < 64 * ENCD; i += 256) tile[i >> 7][i & 127] = src[i];
    __syncthreads();
    int vl = t & 63, ag = t >> 6;          // ag wave-uniform -> W_enc loads go scalar
    for (int ai = 0; ai < 64; ai++) {
        int a = ag * 64 + ai;
        const float* w = W_enc + a * ENCD;
        float acc = 0.f;
        #pragma unroll 8
        for (int k = 0; k < ENCD; k++) acc = fmaf(tile[vl][k], w[k], acc);
        acc += b_enc[a];
        u32 u = __float_as_uint(acc);
        u += 0x7fffu + ((u >> 16) & 1u);   // round-to-nearest-even bf16
        enc_attT[((size_t)b * ATTD + a) * VV + v0 + vl] = (u16)(u >> 16);
    }
}

// mean_enc -> h0,c0 -> dec_att0, gate0, xT(emb0 + h0 rows), lengths output
__global__ __launch_bounds__(512) void k_init(const float* __restrict__ enc,
                                              const int* __restrict__ lens,
                                              const int* __restrict__ captions,
                                              const float* __restrict__ emb_W,
                                              const float* __restrict__ W_init_h,
                                              const float* __restrict__ b_init_h,
                                              const float* __restrict__ W_init_c,
                                              const float* __restrict__ b_init_c,
                                              const float* __restrict__ W_decT,
                                              const float* __restrict__ b_dec,
                                              const float* __restrict__ W_betaT,
                                              const float* __restrict__ b_beta,
                                              float* __restrict__ h, float* __restrict__ c,
                                              float* __restrict__ xT,
                                              float* __restrict__ dec_att,
                                              float* __restrict__ gate,
                                              float* __restrict__ out_len) {
    __shared__ float part[512];
    __shared__ float mean[ENCD];
    __shared__ float h_s[DECD];
    int b = blockIdx.x, t = threadIdx.x;
    int e = t & 127, ch = t >> 7;
    float s = 0.f;
    const float* rowb = enc + (size_t)b * VV * ENCD;
    for (int v = ch * 512; v < ch * 512 + 512; v++) s += rowb[(size_t)v * ENCD + e];
    part[t] = s;
    __syncthreads();
    if (ch == 0) mean[e] = (part[e] + part[128 + e] + part[256 + e] + part[384 + e]) * (1.0f / VV);
    __syncthreads();
    {
        int d = t;
        float hh = b_init_h[d], cc = b_init_c[d];
        for (int k = 0; k < ENCD; k++) {
            hh = fmaf(mean[k], W_init_h[d * ENCD + k], hh);
            cc = fmaf(mean[k], W_init_c[d * ENCD + k], cc);
        }
        h[b * DECD + d] = hh;
        c[b * DECD + d] = cc;
        h_s[d] = hh;
        xT[(384 + d) * BB + b] = hh;       // h part of unified x
    }
    __syncthreads();
    if (t < ATTD) {
        float s2 = b_dec[t];
        for (int l = 0; l < DECD; l++) s2 = fmaf(h_s[l], W_decT[l * ATTD + t], s2);
        dec_att[b * ATTD + t] = s2;
    } else if (t < ATTD + ENCD) {
        int ee = t - ATTD;
        float s2 = b_beta[ee];
        for (int l = 0; l < DECD; l++) s2 = fmaf(h_s[l], W_betaT[l * ENCD + ee], s2);
        gate[b * ENCD + ee] = sigf(s2);
    } else {
        int k = t - 384;
        int cap = captions[b * TT + 0];
        xT[k * BB + b] = emb_W[cap * EMBD + k];
        xT[(k + 128) * BB + b] = emb_W[cap * EMBD + k + 128];
    }
    if (t == 0) out_len[b] = (float)lens[b];
}

// ---------------- per-step kernels ----------------

// scores[b][v] -> exp(scores) into escore; per-b denominator via atomic.
// b_full dropped (softmax shift-invariant); no max-subtraction (|s| < ~2).
__global__ __launch_bounds__(256) void k_scores(const u32* __restrict__ enc_attT2,
                                                const float* __restrict__ dec_att,
                                                const float* __restrict__ w_full,
                                                const int* __restrict__ lens,
                                                float* __restrict__ escore,
                                                float* __restrict__ denom, int tstep) {
    int b = blockIdx.y;
    if (tstep >= lens[b]) return;          // lengths sorted desc: masked rows skip entirely
    __shared__ float sd[ATTD];
    __shared__ float sw[ATTD];
    __shared__ float wsum[4];
    int t = threadIdx.x;
    sd[t] = dec_att[b * ATTD + t];
    sw[t] = w_full[t];
    __syncthreads();
    int v0 = blockIdx.x * 512;             // 2 voxels per thread (packed bf16x2 loads)
    size_t idx = (size_t)b * ATTD * (VV / 2) + (v0 >> 1) + t;
    float s0 = 0.f, s1 = 0.f;
    #pragma unroll 8
    for (int a = 0; a < ATTD; a++) {
        u32 u = enc_attT2[idx];
        idx += (VV / 2);
        float da = sd[a];
        float x0 = __uint_as_float(u << 16) + da;
        float x1 = __uint_as_float(u & 0xffff0000u) + da;
        s0 = fmaf(fmaxf(x0, 0.f), sw[a], s0);
        s1 = fmaf(fmaxf(x1, 0.f), sw[a], s1);
    }
    float e0 = __expf(s0), e1 = __expf(s1);
    ((float2*)escore)[((size_t)b * VV + v0) / 2 + t] = make_float2(e0, e1);
    float ss = e0 + e1;
    for (int o = 32; o > 0; o >>= 1) ss += __shfl_down(ss, o);
    if ((t & 63) == 0) wsum[t >> 6] = ss;
    __syncthreads();
    if (t == 0) atomicAdd(denom + tstep * BB + b, wsum[0] + wsum[1] + wsum[2] + wsum[3]);
}

// alpha = escore/denom -> alphas output + awe[b][e] = sum_v alpha*enc (atomic partial)
__global__ __launch_bounds__(256) void k_awe(const float* __restrict__ enc,
                                             const float* __restrict__ escore,
                                             const float* __restrict__ denom,
                                             const int* __restrict__ lens,
                                             float* __restrict__ awe,
                                             float* __restrict__ alphas, int tstep) {
    int b = blockIdx.y;
    if (tstep >= lens[b]) return;
    int v0 = blockIdx.x * 512;
    float inv = 1.0f / denom[tstep * BB + b];
    int t = threadIdx.x;
    for (int i = t; i < 512; i += 256)
        alphas[((size_t)b * TT + tstep) * VV + v0 + i] = escore[(size_t)b * VV + v0 + i] * inv;
    int e = t & 127, half = t >> 7;
    float acc = 0.f;
    const float* encb = enc + ((size_t)b * VV) * ENCD;
    #pragma unroll 4
    for (int v = v0 + half; v < v0 + 512; v += 2)
        acc = fmaf(escore[(size_t)b * VV + v], encb[(size_t)v * ENCD + e], acc);
    atomicAdd(awe + ((size_t)tstep * BB + b) * ENCD + e, acc * inv);
}

// gates_part[kc][g][b] partial GEMM: unified K = [emb(256) | gated awe(128) | h(512)]
// lane = b, 8 gate rows per wave, weights go through scalar loads (uniform addr).
__global__ __launch_bounds__(256) void k_lstm(const float* __restrict__ xT,
                                              const float* __restrict__ awe,
                                              const float* __restrict__ gate,
                                              const float* __restrict__ W_ih,
                                              const float* __restrict__ W_hh,
                                              const float* __restrict__ b_ih,
                                              const float* __restrict__ b_hh,
                                              float* __restrict__ gates_part, int tstep) {
    __shared__ float gawe[BB][ENCD + 1];   // pad: lane-major reads hit distinct banks
    int gt = blockIdx.x, kc = blockIdx.y;
    int lane = threadIdx.x & 63, wv = threadIdx.x >> 6;
    int gbase = gt * 32 + wv * 8;
    int k0 = kc * 128;
    float acc[8];
    #pragma unroll
    for (int j = 0; j < 8; j++)
        acc[j] = (kc == 0) ? (b_ih[gbase + j] + b_hh[gbase + j]) : 0.f;
    if (kc == 2) {                          // awe columns 256..383
        for (int i = threadIdx.x; i < BB * ENCD; i += 256) {
            int bb = i >> 7, ee = i & 127;
            gawe[bb][ee] = gate[bb * ENCD + ee] * awe[((size_t)tstep * BB + bb) * ENCD + ee];
        }
        __syncthreads();
        for (int kk = 0; kk < 128; kk++) {
            float xv = gawe[lane][kk];
            #pragma unroll
            for (int j = 0; j < 8; j++)
                acc[j] = fmaf(xv, W_ih[(gbase + j) * 384 + 256 + kk], acc[j]);
        }
    } else if (kc < 2) {                    // emb columns 0..255
        for (int kk = 0; kk < 128; kk++) {
            float xv = xT[(k0 + kk) * BB + lane];
            #pragma unroll
            for (int j = 0; j < 8; j++)
                acc[j] = fmaf(xv, W_ih[(gbase + j) * 384 + k0 + kk], acc[j]);
        }
    } else {                                // h columns (W_hh cols 0..511)
        const float* Wh = W_hh + (k0 - 384);
        for (int kk = 0; kk < 128; kk++) {
            float xv = xT[(k0 + kk) * BB + lane];
            #pragma unroll
            for (int j = 0; j < 8; j++)
                acc[j] = fmaf(xv, Wh[(gbase + j) * DECD + kk], acc[j]);
        }
    }
    #pragma unroll
    for (int j = 0; j < 8; j++)
        gates_part[((size_t)kc * 2048 + gbase + j) * BB + lane] = acc[j];
}

// cell update + predictions + next-step dec_att/gate/emb staging
__global__ __launch_bounds__(512) void k_cell(const float* __restrict__ gates_part,
                                              const int* __restrict__ lens,
                                              const int* __restrict__ captions,
                                              const float* __restrict__ emb_W,
                                              const float* __restrict__ W_final,
                                              const float* __restrict__ b_final,
                                              const float* __restrict__ W_decT,
                                              const float* __restrict__ b_dec,
                                              const float* __restrict__ W_betaT,
                                              const float* __restrict__ b_beta,
                                              float* __restrict__ h, float* __restrict__ c,
                                              float* __restrict__ xT,
                                              float* __restrict__ dec_att,
                                              float* __restrict__ gate,
                                              float* __restrict__ preds, int tstep) {
    int b = blockIdx.x;
    if (tstep >= lens[b]) return;           // masked rows: h,c,xT,dec_att,gate all stay stale=correct
    __shared__ float h_s[DECD];
    int d = threadIdx.x;
    float gi = 0.f, gf = 0.f, gg = 0.f, go = 0.f;
    #pragma unroll
    for (int kc = 0; kc < 7; kc++) {
        const float* gp = gates_part + (size_t)kc * 2048 * BB + b;
        gi += gp[(size_t)d * BB];
        gf += gp[(size_t)(512 + d) * BB];
        gg += gp[(size_t)(1024 + d) * BB];
        go += gp[(size_t)(1536 + d) * BB];
    }
    gi = sigf(gi); gf = sigf(gf); go = sigf(go); gg = tanhf(gg);
    float cn = gf * c[b * DECD + d] + gi * gg;
    float hn = go * tanhf(cn);
    c[b * DECD + d] = cn;
    h[b * DECD + d] = hn;
    h_s[d] = hn;
    xT[(384 + d) * BB + b] = hn;
    __syncthreads();
    // predictions: 8 waves cover 29 vocab outputs, shuffle-reduce over K=512
    int lane = d & 63, wv = d >> 6;
    for (int j = wv; j < NVOCAB; j += 8) {
        float s = 0.f;
        #pragma unroll
        for (int i = 0; i < 8; i++)
            s = fmaf(h_s[lane + 64 * i], W_final[j * DECD + lane + 64 * i], s);
        for (int o = 32; o > 0; o >>= 1) s += __shfl_down(s, o);
        if (lane == 0) preds[((size_t)b * TT + tstep) * NVOCAB + j] = s + b_final[j];
    }
    // next step's dec_att / gate / embedding
    if (d < ATTD) {
        float s = b_dec[d];
        for (int l = 0; l < DECD; l++) s = fmaf(h_s[l], W_decT[l * ATTD + d], s);
        dec_att[b * ATTD + d] = s;
    } else if (d < ATTD + ENCD) {
        int ee = d - ATTD;
        float s = b_beta[ee];
        for (int l = 0; l < DECD; l++) s = fmaf(h_s[l], W_betaT[l * ENCD + ee], s);
        gate[b * ENCD + ee] = sigf(s);
    } else if (tstep + 1 < TT) {
        int k = d - 384;
        int cap = captions[b * TT + tstep + 1];
        xT[k * BB + b] = emb_W[cap * EMBD + k];
        xT[(k + 128) * BB + b] = emb_W[cap * EMBD + k + 128];
    }
}

extern "C" void kernel_launch(void* const* d_in, const int* in_sizes, int n_in,
                              void* d_out, int out_size, void* d_ws, size_t ws_size,
                              hipStream_t stream) {
    const float* enc      = (const float*)d_in[0];
    const int*   captions = (const int*)d_in[1];
    const int*   lens     = (const int*)d_in[2];
    const float* emb_W    = (const float*)d_in[3];
    const float* W_enc    = (const float*)d_in[4];
    const float* b_enc    = (const float*)d_in[5];
    const float* W_dec    = (const float*)d_in[6];
    const float* b_dec    = (const float*)d_in[7];
    const float* w_full   = (const float*)d_in[8];
    // d_in[9] b_full: unused — softmax is shift-invariant
    const float* W_ih     = (const float*)d_in[10];
    const float* b_ih     = (const float*)d_in[11];
    const float* W_hh     = (const float*)d_in[12];
    const float* b_hh     = (const float*)d_in[13];
    const float* W_init_h = (const float*)d_in[14];
    const float* b_init_h = (const float*)d_in[15];
    const float* W_init_c = (const float*)d_in[16];
    const float* b_init_c = (const float*)d_in[17];
    const float* W_beta   = (const float*)d_in[18];
    const float* b_beta   = (const float*)d_in[19];
    const float* W_final  = (const float*)d_in[20];
    const float* b_final  = (const float*)d_in[21];

    float* preds   = (float*)d_out;                      // [B][T][VOCAB]
    float* alphas  = preds + (size_t)BB * TT * NVOCAB;   // [B][T][V]
    float* out_len = alphas + (size_t)BB * TT * VV;      // [B] (written as float)

    char* ws = (char*)d_ws;
    size_t off = 0;
    auto alloc = [&](size_t bytes) {
        char* p = ws + off;
        off += (bytes + 255) & ~(size_t)255;
        return p;
    };
    u16*   enc_attT   = (u16*)  alloc((size_t)BB * ATTD * VV * sizeof(u16));   // 67 MB
    float* escore     = (float*)alloc((size_t)BB * VV * sizeof(float));
    char*  zbase      = ws + off;                                              // zeroed region start
    float* denom      = (float*)alloc((size_t)TT * BB * sizeof(float));
    float* awe        = (float*)alloc((size_t)TT * BB * ENCD * sizeof(float));
    size_t zbytes     = (size_t)((ws + off) - zbase);
    float* dec_att    = (float*)alloc((size_t)BB * ATTD * sizeof(float));
    float* gate       = (float*)alloc((size_t)BB * ENCD * sizeof(float));
    float* xT         = (float*)alloc((size_t)896 * BB * sizeof(float));
    float* gates_part = (float*)alloc((size_t)7 * 2048 * BB * sizeof(float));
    float* h          = (float*)alloc((size_t)BB * DECD * sizeof(float));
    float* c          = (float*)alloc((size_t)BB * DECD * sizeof(float));
    float* W_decT     = (float*)alloc((size_t)DECD * ATTD * sizeof(float));
    float* W_betaT    = (float*)alloc((size_t)DECD * ENCD * sizeof(float));

    // masked (b,t) outputs must be exactly 0; atomic targets must start at 0
    hipMemsetAsync(d_out, 0, (size_t)out_size * sizeof(float), stream);
    hipMemsetAsync(zbase, 0, zbytes, stream);

    k_transpose<<<768, 256, 0, stream>>>(W_dec, W_beta, W_decT, W_betaT);
    k_enc_att<<<dim3(VV / 64, BB), 256, 0, stream>>>(enc, W_enc, b_enc, enc_attT);
    k_init<<<BB, 512, 0, stream>>>(enc, lens, captions, emb_W, W_init_h, b_init_h,
                                   W_init_c, b_init_c, W_decT, b_dec, W_betaT, b_beta,
                                   h, c, xT, dec_att, gate, out_len);

    for (int t = 0; t < TT; t++) {
        k_scores<<<dim3(4, BB), 256, 0, stream>>>((const u32*)enc_attT, dec_att, w_full,
                                                  lens, escore, denom, t);
        k_awe<<<dim3(4, BB), 256, 0, stream>>>(enc, escore, denom, lens, awe, alphas, t);
        k_lstm<<<dim3(64, 7), 256, 0, stream>>>(xT, awe, gate, W_ih, W_hh, b_ih, b_hh,
                                                gates_part, t);
        k_cell<<<BB, 512, 0, stream>>>(gates_part, lens, captions, emb_W, W_final, b_final,
                                       W_decT, b_dec, W_betaT, b_beta, h, c, xT, dec_att,
                                       gate, preds, t);
    }
}